// Round 1
// baseline (337.701 us; speedup 1.0000x reference)
//
#include <hip/hip_runtime.h>
#include <hip/hip_fp16.h>
#include <cstddef>
#include <cstdint>

#define N_PTS 16384
#define K_PTS 1024
#define D_DIM 512
#define EPS_F 0.1f
#define ITERS 20
#define MU_F (1.0f/16384.0f)
#define NU_F (1.0f/1024.0f)
#define NCOPY 8
#define SINK_BLOCKS 256
#define FLAG_STRIDE 16   // 64B padding per flag
#define ACC_TOTAL ((ITERS + 1) * NCOPY * K_PTS)

// workspace layout (bytes)
#define WS_ACCUM_BYTES ((size_t)ACC_TOTAL * 4)                    // 688128
#define WS_FLAGS_BYTES ((size_t)SINK_BLOCKS * FLAG_STRIDE * 4)    // 16384
#define WS_MAX_BYTES   ((size_t)16)
#define WS_XN_BYTES    ((size_t)N_PTS * 4)                        // 65536
#define WS_PN_BYTES    ((size_t)K_PTS * 4)                        // 4096
#define WS_XH_BYTES    ((size_t)N_PTS * D_DIM * 2)                // 16 MiB
#define WS_PH_BYTES    ((size_t)K_PTS * D_DIM * 2)                // 1 MiB

typedef float f32x4 __attribute__((ext_vector_type(4)));
typedef short s16x8 __attribute__((ext_vector_type(8)));

__device__ __forceinline__ float wave_reduce_sum(float s) {
#pragma unroll
  for (int off = 32; off > 0; off >>= 1) s += __shfl_xor(s, off, 64);
  return s;
}
__device__ __forceinline__ float wave_reduce_max(float s) {
#pragma unroll
  for (int off = 32; off > 0; off >>= 1) s = fmaxf(s, __shfl_xor(s, off, 64));
  return s;
}

// async 16B global->LDS (linear LDS dest: uniform base + lane*16)
__device__ __forceinline__ void gl16(const void* g, void* l) {
  __builtin_amdgcn_global_load_lds(
      (const __attribute__((address_space(1))) unsigned int*)g,
      (__attribute__((address_space(3))) unsigned int*)l, 16, 0, 0);
}

// ---------------------------------------------------------------- init
__global__ __launch_bounds__(256) void init_kernel(float* __restrict__ accum,
                                                   unsigned int* __restrict__ flags,
                                                   unsigned int* __restrict__ maxbits,
                                                   float* __restrict__ loss) {
  int i = blockIdx.x * 256 + threadIdx.x;
  if (i < ACC_TOTAL) accum[i] = 0.0f;
  if (i < SINK_BLOCKS * FLAG_STRIDE) flags[i] = 0u;
  if (i == 0) { *maxbits = 0u; *loss = 0.0f; }
}

// ---------------------------------------------------------------- convert pass
// fp32 -> {hi,lo} truncated-bf16 split, row-major, plus fused row sum-of-squares.
// One wave per row (512 floats): lane handles 8 consecutive floats.
__global__ __launch_bounds__(256) void convert_kernel(const float* __restrict__ X,
                                                      const float* __restrict__ P,
                                                      unsigned short* __restrict__ Xh,
                                                      unsigned short* __restrict__ Xl,
                                                      unsigned short* __restrict__ Ph,
                                                      unsigned short* __restrict__ Pl,
                                                      float* __restrict__ xn,
                                                      float* __restrict__ pn) {
  const int gw = (blockIdx.x * 256 + threadIdx.x) >> 6;  // global wave id = row id
  const int lane = threadIdx.x & 63;

  const float* src;
  unsigned short *dh, *dl;
  float* nrm;
  if (gw < N_PTS) {
    src = X + (size_t)gw * D_DIM;
    dh = Xh + (size_t)gw * D_DIM;
    dl = Xl + (size_t)gw * D_DIM;
    nrm = xn + gw;
  } else {
    int r = gw - N_PTS;
    src = P + (size_t)r * D_DIM;
    dh = Ph + (size_t)r * D_DIM;
    dl = Pl + (size_t)r * D_DIM;
    nrm = pn + r;
  }

  float4 f0 = *(const float4*)(src + lane * 8);
  float4 f1 = *(const float4*)(src + lane * 8 + 4);
  float f[8] = {f0.x, f0.y, f0.z, f0.w, f1.x, f1.y, f1.z, f1.w};

  float s = 0.f;
#pragma unroll
  for (int j = 0; j < 8; j++) s += f[j] * f[j];

  unsigned int hu[4], lu[4];
#pragma unroll
  for (int j = 0; j < 4; j++) {
    unsigned int a0 = __float_as_uint(f[2 * j]), a1 = __float_as_uint(f[2 * j + 1]);
    hu[j] = __builtin_amdgcn_perm(a1, a0, 0x07060302u);
    unsigned int l0 = __float_as_uint(f[2 * j]     - __uint_as_float(a0 & 0xffff0000u));
    unsigned int l1 = __float_as_uint(f[2 * j + 1] - __uint_as_float(a1 & 0xffff0000u));
    lu[j] = __builtin_amdgcn_perm(l1, l0, 0x07060302u);
  }
  *(uint4*)(dh + lane * 8) = make_uint4(hu[0], hu[1], hu[2], hu[3]);
  *(uint4*)(dl + lane * 8) = make_uint4(lu[0], lu[1], lu[2], lu[3]);

  s = wave_reduce_sum(s);
  if (lane == 0) *nrm = s;
}

// ---------------------------------------------------------------- fast GEMM (pre-split bf16)
// C(fp16) = |x|^2 + |p|^2 - 2*x@p^T via 3-term split-bf16 MFMA.
// 128x128 tile, BK=64 halfs, 4 tiles staged via global_load_lds dwordx4.
// T2 XOR-swizzle: linear LDS dest + pre-swizzled per-lane GLOBAL source + same XOR on ds_read.
__global__ __launch_bounds__(256, 2) void gemm2_kernel(const unsigned short* __restrict__ Xh,
                                                       const unsigned short* __restrict__ Xl,
                                                       const unsigned short* __restrict__ Ph,
                                                       const unsigned short* __restrict__ Pl,
                                                       const float* __restrict__ xn,
                                                       const float* __restrict__ pn,
                                                       __half* __restrict__ Ch,
                                                       unsigned int* __restrict__ maxbits) {
  __shared__ __align__(16) unsigned short Ah[128 * 64];  // 16 KB each
  __shared__ __align__(16) unsigned short Al[128 * 64];
  __shared__ __align__(16) unsigned short Bh[128 * 64];
  __shared__ __align__(16) unsigned short Bl[128 * 64];
  __shared__ float wmax[4];

  const int tid = threadIdx.x;
  const int lane = tid & 63, wv = tid >> 6;
  const int wm = wv >> 1, wn = wv & 1;
  const int m0 = blockIdx.y * 128, k0 = blockIdx.x * 128;

  // staging geometry: chunk = wv*4+is covers rows [chunk*8, chunk*8+8), 8 lanes/row.
  // row&7 == lane>>3 for every chunk; granule g == lane&7; swizzled source granule = g^(row&7).
  const int srow = lane >> 3;                       // row within 8-row chunk
  const int sswg = ((lane & 7) ^ srow) << 4;        // swizzled granule byte offset (const)
  const char* gAh = (const char*)(Xh + (size_t)m0 * D_DIM);
  const char* gAl = (const char*)(Xl + (size_t)m0 * D_DIM);
  const char* gBh = (const char*)(Ph + (size_t)k0 * D_DIM);
  const char* gBl = (const char*)(Pl + (size_t)k0 * D_DIM);

  f32x4 acc[4][4] = {};

  for (int d0 = 0; d0 < D_DIM; d0 += 64) {
    if (d0) __syncthreads();  // previous iteration's fragment reads must finish
#pragma unroll
    for (int is = 0; is < 4; is++) {
      const int chunk = wv * 4 + is;
      const size_t rb = (size_t)(chunk * 8 + srow) * (D_DIM * 2) + (size_t)d0 * 2 + sswg;
      void* lb_a = &Ah[chunk * 512];
      void* lb_b = &Bh[chunk * 512];
      void* lb_al = &Al[chunk * 512];
      void* lb_bl = &Bl[chunk * 512];
      gl16(gAh + rb, lb_a);
      gl16(gAl + rb, lb_al);
      gl16(gBh + rb, lb_b);
      gl16(gBl + rb, lb_bl);
    }
    __syncthreads();  // compiler drains vmcnt(0) before s_barrier

    // B fragments for both k-subtiles
    s16x8 bh[2][4], bl[2][4];
#pragma unroll
    for (int ks = 0; ks < 2; ks++)
#pragma unroll
      for (int ni = 0; ni < 4; ni++) {
        int rB = wn * 64 + ni * 16 + (lane & 15);
        int g = (ks * 4 + (lane >> 4)) ^ (rB & 7);
        bh[ks][ni] = *(const s16x8*)&Bh[rB * 64 + g * 8];
        bl[ks][ni] = *(const s16x8*)&Bl[rB * 64 + g * 8];
      }
#pragma unroll
    for (int mi = 0; mi < 4; mi++) {
      int rA = wm * 64 + mi * 16 + (lane & 15);
      int g0 = (0 + (lane >> 4)) ^ (rA & 7);
      int g1 = (4 + (lane >> 4)) ^ (rA & 7);
      s16x8 a0h = *(const s16x8*)&Ah[rA * 64 + g0 * 8];
      s16x8 a1h = *(const s16x8*)&Ah[rA * 64 + g1 * 8];
      s16x8 a0l = *(const s16x8*)&Al[rA * 64 + g0 * 8];
      s16x8 a1l = *(const s16x8*)&Al[rA * 64 + g1 * 8];
#pragma unroll
      for (int ni = 0; ni < 4; ni++) {
        acc[mi][ni] = __builtin_amdgcn_mfma_f32_16x16x32_bf16(a0h, bh[0][ni], acc[mi][ni], 0, 0, 0);
        acc[mi][ni] = __builtin_amdgcn_mfma_f32_16x16x32_bf16(a1h, bh[1][ni], acc[mi][ni], 0, 0, 0);
        acc[mi][ni] = __builtin_amdgcn_mfma_f32_16x16x32_bf16(a0h, bl[0][ni], acc[mi][ni], 0, 0, 0);
        acc[mi][ni] = __builtin_amdgcn_mfma_f32_16x16x32_bf16(a1h, bl[1][ni], acc[mi][ni], 0, 0, 0);
        acc[mi][ni] = __builtin_amdgcn_mfma_f32_16x16x32_bf16(a0l, bh[0][ni], acc[mi][ni], 0, 0, 0);
        acc[mi][ni] = __builtin_amdgcn_mfma_f32_16x16x32_bf16(a1l, bh[1][ni], acc[mi][ni], 0, 0, 0);
      }
    }
  }

  // epilogue: C/D layout col=lane&15, row=(lane>>4)*4+reg; norms from convert pass
  float lmax = -3.4e38f;
#pragma unroll
  for (int mi = 0; mi < 4; mi++) {
    int rloc = wm * 64 + mi * 16 + (lane >> 4) * 4;
    float dxv[4];
#pragma unroll
    for (int r = 0; r < 4; r++) dxv[r] = xn[m0 + rloc + r];
#pragma unroll
    for (int ni = 0; ni < 4; ni++) {
      int cloc = wn * 64 + ni * 16 + (lane & 15);
      float pnc = pn[k0 + cloc];
#pragma unroll
      for (int r = 0; r < 4; r++) {
        float val = dxv[r] + pnc - 2.0f * acc[mi][ni][r];
        Ch[(size_t)(m0 + rloc + r) * K_PTS + k0 + cloc] = __float2half(val);
        lmax = fmaxf(lmax, val);
      }
    }
  }
  lmax = wave_reduce_max(lmax);
  if (lane == 0) wmax[wv] = lmax;
  __syncthreads();
  if (tid == 0) {
    float m = fmaxf(fmaxf(wmax[0], wmax[1]), fmaxf(wmax[2], wmax[3]));
    atomicMax((int*)maxbits, __float_as_int(m));  // global max is positive
  }
}

// ---------------------------------------------------------------- fallback GEMM (proven path)
// Used only if ws_size can't hold the converted operands.
__global__ __launch_bounds__(256) void gemm_kernel(const float* __restrict__ X,
                                                   const float* __restrict__ P,
                                                   __half* __restrict__ Ch,
                                                   unsigned int* __restrict__ maxbits) {
  __shared__ __align__(16) unsigned short Ah[128 * 32];
  __shared__ __align__(16) unsigned short Al[128 * 32];
  __shared__ __align__(16) unsigned short Bh[128 * 32];
  __shared__ __align__(16) unsigned short Bl[128 * 32];
  __shared__ float dxs[128];
  __shared__ float pns[128];

  const int tid = threadIdx.x;
  const int lane = tid & 63, wv = tid >> 6;
  const int wm = wv >> 1, wn = wv & 1;
  const int m0 = blockIdx.y * 128, k0 = blockIdx.x * 128;
  const int lrow = tid >> 1, lhalf = tid & 1;

  const float* xrow = X + (size_t)(m0 + lrow) * D_DIM + lhalf * 16;
  const float* prow = P + (size_t)(k0 + lrow) * D_DIM + lhalf * 16;
  const int sw = (lrow >> 1) & 3;
  const int woff0 = lrow * 32 + ((2 * lhalf + 0) ^ sw) * 8;
  const int woff1 = lrow * 32 + ((2 * lhalf + 1) ^ sw) * 8;

  f32x4 acc[4][4] = {};
  float sx = 0.f, sp = 0.f;

  for (int d0 = 0; d0 < D_DIM; d0 += 32) {
    float av[16], bv[16];
    {
      const float4* xp = (const float4*)(xrow + d0);
      const float4* pp = (const float4*)(prow + d0);
#pragma unroll
      for (int q = 0; q < 4; q++) {
        float4 a = xp[q], b = pp[q];
        av[q*4+0]=a.x; av[q*4+1]=a.y; av[q*4+2]=a.z; av[q*4+3]=a.w;
        bv[q*4+0]=b.x; bv[q*4+1]=b.y; bv[q*4+2]=b.z; bv[q*4+3]=b.w;
      }
    }
#pragma unroll
    for (int q = 0; q < 16; q++) { sx += av[q] * av[q]; sp += bv[q] * bv[q]; }
    unsigned int ahu[8], alu[8], bhu[8], blu[8];
#pragma unroll
    for (int j = 0; j < 8; j++) {
      unsigned int a0 = __float_as_uint(av[2*j]), a1 = __float_as_uint(av[2*j+1]);
      ahu[j] = __builtin_amdgcn_perm(a1, a0, 0x07060302u);
      unsigned int l0 = __float_as_uint(av[2*j]   - __uint_as_float(a0 & 0xffff0000u));
      unsigned int l1 = __float_as_uint(av[2*j+1] - __uint_as_float(a1 & 0xffff0000u));
      alu[j] = __builtin_amdgcn_perm(l1, l0, 0x07060302u);
      unsigned int b0 = __float_as_uint(bv[2*j]), b1 = __float_as_uint(bv[2*j+1]);
      bhu[j] = __builtin_amdgcn_perm(b1, b0, 0x07060302u);
      unsigned int m0u = __float_as_uint(bv[2*j]   - __uint_as_float(b0 & 0xffff0000u));
      unsigned int m1u = __float_as_uint(bv[2*j+1] - __uint_as_float(b1 & 0xffff0000u));
      blu[j] = __builtin_amdgcn_perm(m1u, m0u, 0x07060302u);
    }
    __syncthreads();
    *(uint4*)&Ah[woff0] = make_uint4(ahu[0], ahu[1], ahu[2], ahu[3]);
    *(uint4*)&Ah[woff1] = make_uint4(ahu[4], ahu[5], ahu[6], ahu[7]);
    *(uint4*)&Al[woff0] = make_uint4(alu[0], alu[1], alu[2], alu[3]);
    *(uint4*)&Al[woff1] = make_uint4(alu[4], alu[5], alu[6], alu[7]);
    *(uint4*)&Bh[woff0] = make_uint4(bhu[0], bhu[1], bhu[2], bhu[3]);
    *(uint4*)&Bh[woff1] = make_uint4(bhu[4], bhu[5], bhu[6], bhu[7]);
    *(uint4*)&Bl[woff0] = make_uint4(blu[0], blu[1], blu[2], blu[3]);
    *(uint4*)&Bl[woff1] = make_uint4(blu[4], blu[5], blu[6], blu[7]);
    __syncthreads();

    s16x8 ah[4], al[4], bh[4], bl[4];
#pragma unroll
    for (int i = 0; i < 4; i++) {
      int rA = wm * 64 + i * 16 + (lane & 15);
      int gA = (lane >> 4) ^ ((rA >> 1) & 3);
      ah[i] = *(const s16x8*)&Ah[rA * 32 + gA * 8];
      al[i] = *(const s16x8*)&Al[rA * 32 + gA * 8];
      int rB = wn * 64 + i * 16 + (lane & 15);
      int gB = (lane >> 4) ^ ((rB >> 1) & 3);
      bh[i] = *(const s16x8*)&Bh[rB * 32 + gB * 8];
      bl[i] = *(const s16x8*)&Bl[rB * 32 + gB * 8];
    }
#pragma unroll
    for (int mi = 0; mi < 4; mi++)
#pragma unroll
      for (int ni = 0; ni < 4; ni++) {
        acc[mi][ni] = __builtin_amdgcn_mfma_f32_16x16x32_bf16(ah[mi], bh[ni], acc[mi][ni], 0, 0, 0);
        acc[mi][ni] = __builtin_amdgcn_mfma_f32_16x16x32_bf16(ah[mi], bl[ni], acc[mi][ni], 0, 0, 0);
        acc[mi][ni] = __builtin_amdgcn_mfma_f32_16x16x32_bf16(al[mi], bh[ni], acc[mi][ni], 0, 0, 0);
      }
  }

  float px = sx + __shfl_xor(sx, 1, 64);
  float pp2 = sp + __shfl_xor(sp, 1, 64);
  __syncthreads();
  dxs[lrow] = px;
  pns[lrow] = pp2;
  __syncthreads();

  float lmax = -3.4e38f;
#pragma unroll
  for (int mi = 0; mi < 4; mi++) {
    int rloc = wm * 64 + mi * 16 + (lane >> 4) * 4;
    float dxv[4];
#pragma unroll
    for (int r = 0; r < 4; r++) dxv[r] = dxs[rloc + r];
#pragma unroll
    for (int ni = 0; ni < 4; ni++) {
      int cloc = wn * 64 + ni * 16 + (lane & 15);
      float pnc = pns[cloc];
#pragma unroll
      for (int r = 0; r < 4; r++) {
        float val = dxv[r] + pnc - 2.0f * acc[mi][ni][r];
        Ch[(size_t)(m0 + rloc + r) * K_PTS + k0 + cloc] = __float2half(val);
        lmax = fmaxf(lmax, val);
      }
    }
  }
  lmax = wave_reduce_max(lmax);
  __shared__ float wmax[4];
  if (lane == 0) wmax[wv] = lmax;
  __syncthreads();
  if (tid == 0) {
    float m = fmaxf(fmaxf(wmax[0], wmax[1]), fmaxf(wmax[2], wmax[3]));
    atomicMax((int*)maxbits, __float_as_int(m));
  }
}

// ---------------------------------------------------------------- persistent Sinkhorn, fully fused
// (unchanged from verified version)
__global__ __launch_bounds__(512, 2) void sinkhorn_kernel(
    const __half* __restrict__ Ch,
    const unsigned int* __restrict__ maxbits,
    float* __restrict__ accum,          // (ITERS+1) x NCOPY x K_PTS
    unsigned int* __restrict__ flags,   // SINK_BLOCKS x FLAG_STRIDE
    float* __restrict__ T,
    float* __restrict__ loss) {
  __shared__ float v_lds[K_PTS];
  __shared__ float red[8][K_PTS];
  const int tid = threadIdx.x;
  const int lane = tid & 63, wv = tid >> 6;
  const int b = blockIdx.x;
  const int r0 = b * 64 + wv * 8;

  float factor;
  {
    float cmax = __int_as_float((int)*maxbits);
    factor = -1.0f / ((cmax + 1e-8f) * EPS_F);
  }
  f32x4 k4[32];
#pragma unroll
  for (int i = 0; i < 8; i++) {
    const __half* rp = Ch + (size_t)(r0 + i) * K_PTS + lane;
#pragma unroll
    for (int q = 0; q < 4; q++) {
      f32x4 kk;
#pragma unroll
      for (int e = 0; e < 4; e++)
        kk[e] = __expf(__half2float(rp[(4 * q + e) * 64]) * factor);
      k4[i * 4 + q] = kk;
    }
  }
  v_lds[tid * 2 + 0] = 1.0f;
  v_lds[tid * 2 + 1] = 1.0f;
  __syncthreads();

  float su[8];
  for (int t = 0; t < ITERS; t++) {
    f32x4 vr4[4];
#pragma unroll
    for (int q = 0; q < 4; q++)
#pragma unroll
      for (int e = 0; e < 4; e++)
        vr4[q][e] = v_lds[(4 * q + e) * 64 + lane];

    float s[8];
#pragma unroll
    for (int i = 0; i < 8; i++) {
      f32x4 d = k4[i * 4 + 0] * vr4[0] + k4[i * 4 + 1] * vr4[1]
              + k4[i * 4 + 2] * vr4[2] + k4[i * 4 + 3] * vr4[3];
      s[i] = d[0] + d[1] + d[2] + d[3];
    }
    {
      const bool h32 = (lane & 32) != 0;
      float a[4];
#pragma unroll
      for (int i = 0; i < 4; i++) {
        float x = h32 ? s[i] : s[i + 4];
        float y = h32 ? s[i + 4] : s[i];
        a[i] = y + __shfl_xor(x, 32, 64);
      }
      const bool h16 = (lane & 16) != 0;
      float c[2];
#pragma unroll
      for (int i = 0; i < 2; i++) {
        float x = h16 ? a[i] : a[i + 2];
        float y = h16 ? a[i + 2] : a[i];
        c[i] = y + __shfl_xor(x, 16, 64);
      }
      const bool h8 = (lane & 8) != 0;
      float x = h8 ? c[0] : c[1];
      float y = h8 ? c[1] : c[0];
      float w = y + __shfl_xor(x, 8, 64);
      w += __shfl_xor(w, 4, 64);
      w += __shfl_xor(w, 2, 64);
      w += __shfl_xor(w, 1, 64);
      float ui_local = MU_F / (w + 1e-8f);
#pragma unroll
      for (int i = 0; i < 8; i++)
        su[i] = __uint_as_float(__builtin_amdgcn_readlane(__float_as_uint(ui_local), i * 8));
    }
    f32x4 ca4[4] = {};
#pragma unroll
    for (int i = 0; i < 8; i++)
#pragma unroll
      for (int q = 0; q < 4; q++)
        ca4[q] += su[i] * k4[i * 4 + q];

    __syncthreads();
#pragma unroll
    for (int q = 0; q < 4; q++)
#pragma unroll
      for (int e = 0; e < 4; e++)
        red[wv][(4 * q + e) * 64 + lane] = ca4[q][e];
    __syncthreads();
    {
      float s0 = 0.f, s1 = 0.f;
#pragma unroll
      for (int w8 = 0; w8 < 8; w8++) {
        float2 v2 = *(const float2*)&red[w8][tid * 2];
        s0 += v2.x; s1 += v2.y;
      }
      float* dst = accum + (size_t)(t + 1) * (NCOPY * K_PTS)
                 + (size_t)(b & (NCOPY - 1)) * K_PTS + tid * 2;
      atomicAdd(dst + 0, s0);
      atomicAdd(dst + 1, s1);
    }
    __syncthreads();
    if (tid == 0)
      __hip_atomic_store(&flags[(size_t)b * FLAG_STRIDE], (unsigned)(t + 1),
                         __ATOMIC_RELEASE, __HIP_MEMORY_SCOPE_AGENT);
    if (tid < SINK_BLOCKS) {
      while (__hip_atomic_load(&flags[(size_t)tid * FLAG_STRIDE],
                               __ATOMIC_RELAXED, __HIP_MEMORY_SCOPE_AGENT) < (unsigned)(t + 1))
        __builtin_amdgcn_s_sleep(4);
    }
    __syncthreads();
    {
      float* st = accum + (size_t)(t + 1) * (NCOPY * K_PTS);
      float s0 = 0.f, s1 = 0.f;
#pragma unroll
      for (int c = 0; c < NCOPY; c++) {
        s0 += __hip_atomic_load(st + (size_t)c * K_PTS + tid * 2 + 0,
                                __ATOMIC_RELAXED, __HIP_MEMORY_SCOPE_AGENT);
        s1 += __hip_atomic_load(st + (size_t)c * K_PTS + tid * 2 + 1,
                                __ATOMIC_RELAXED, __HIP_MEMORY_SCOPE_AGENT);
      }
      v_lds[tid * 2 + 0] = NU_F / (s0 + 1e-8f);
      v_lds[tid * 2 + 1] = NU_F / (s1 + 1e-8f);
    }
    __syncthreads();
  }

  float lsum = 0.f;
#pragma unroll
  for (int i = 0; i < 8; i++) {
    float* Trow = T + (size_t)(r0 + i) * K_PTS + lane;
#pragma unroll
    for (int q = 0; q < 4; q++) {
#pragma unroll
      for (int e = 0; e < 4; e++) {
        int c = (4 * q + e) * 64;
        float kk = k4[i * 4 + q][e];
        float tv = su[i] * kk * v_lds[c + lane];
        Trow[c] = tv;
        lsum += tv * (-EPS_F * __logf(kk));
      }
    }
  }
  lsum = wave_reduce_sum(lsum);
  __shared__ float wsum[8];
  if (lane == 0) wsum[wv] = lsum;
  __syncthreads();
  if (tid == 0) {
    float m = 0.f;
#pragma unroll
    for (int i = 0; i < 8; i++) m += wsum[i];
    atomicAdd(loss, m);
  }
}

// ---------------------------------------------------------------- launcher
extern "C" void kernel_launch(void* const* d_in, const int* in_sizes, int n_in,
                              void* d_out, int out_size, void* d_ws, size_t ws_size,
                              hipStream_t stream) {
  const float* x = (const float*)d_in[0];
  const float* p = (const float*)d_in[1];
  float* T = (float*)d_out;
  float* loss = (float*)d_out + (size_t)N_PTS * K_PTS;
  __half* Ch = (__half*)d_out;  // fp16 C staged in d_out between gemm and sinkhorn

  char* wsb = (char*)d_ws;
  size_t off = 0;
  float* accum = (float*)(wsb + off);           off += WS_ACCUM_BYTES;
  unsigned int* flags = (unsigned int*)(wsb + off); off += WS_FLAGS_BYTES;
  unsigned int* maxbits = (unsigned int*)(wsb + off); off += WS_MAX_BYTES;
  float* xn = (float*)(wsb + off);              off += WS_XN_BYTES;
  float* pn = (float*)(wsb + off);              off += WS_PN_BYTES;
  unsigned short* Xh = (unsigned short*)(wsb + off); off += WS_XH_BYTES;
  unsigned short* Xl = (unsigned short*)(wsb + off); off += WS_XH_BYTES;
  unsigned short* Ph = (unsigned short*)(wsb + off); off += WS_PH_BYTES;
  unsigned short* Pl = (unsigned short*)(wsb + off); off += WS_PH_BYTES;
  const size_t ws_need = off;

  init_kernel<<<(ACC_TOTAL + 255) / 256, 256, 0, stream>>>(accum, flags, maxbits, loss);
  if (ws_size >= ws_need) {
    convert_kernel<<<(N_PTS + K_PTS) / 4, 256, 0, stream>>>(x, p, Xh, Xl, Ph, Pl, xn, pn);
    gemm2_kernel<<<dim3(K_PTS / 128, N_PTS / 128), 256, 0, stream>>>(Xh, Xl, Ph, Pl, xn, pn, Ch, maxbits);
  } else {
    gemm_kernel<<<dim3(K_PTS / 128, N_PTS / 128), 256, 0, stream>>>(x, p, Ch, maxbits);
  }
  sinkhorn_kernel<<<SINK_BLOCKS, 512, 0, stream>>>(Ch, maxbits, accum, flags, T, loss);
}

// Round 2
// 325.640 us; speedup vs baseline: 1.0370x; 1.0370x over previous
//
#include <hip/hip_runtime.h>
#include <hip/hip_fp16.h>
#include <cstddef>
#include <cstdint>

#define N_PTS 16384
#define K_PTS 1024
#define D_DIM 512
#define EPS_F 0.1f
#define ITERS 20
#define MU_F (1.0f/16384.0f)
#define NU_F (1.0f/1024.0f)
#define NCOPY 8
#define SINK_BLOCKS 256
#define FLAG_STRIDE 16   // 64B padding per flag
#define ACC_TOTAL ((ITERS + 1) * NCOPY * K_PTS)

// workspace layout (bytes) — fast path needs only ~2.86 MB
#define WS_ACCUM_BYTES ((size_t)ACC_TOTAL * 4)                    // 688128
#define WS_FLAGS_BYTES ((size_t)SINK_BLOCKS * FLAG_STRIDE * 4)    // 16384
#define WS_MAX_BYTES   ((size_t)16)
#define WS_XN_BYTES    ((size_t)N_PTS * 4)                        // 65536
#define WS_PN_BYTES    ((size_t)K_PTS * 4)                        // 4096
#define WS_PH_BYTES    ((size_t)K_PTS * D_DIM * 2)                // 1 MiB each (Ph, Pl)

// d_out layout (64 MiB + 4 B):
//   [0,        32 MiB)  Ch   (fp16 C, staged between gemm and sinkhorn)
//   [32 MiB,   48 MiB)  Xh   (bf16 hi split of X)
//   [48 MiB,   64 MiB)  Xl   (bf16 lo split of X)
//   [64 MiB]            loss
// T's final write covers [0, 64 MiB) but happens after all Ch/Xh/Xl reads.

typedef float f32x4 __attribute__((ext_vector_type(4)));
typedef short s16x8 __attribute__((ext_vector_type(8)));

__device__ __forceinline__ float wave_reduce_sum(float s) {
#pragma unroll
  for (int off = 32; off > 0; off >>= 1) s += __shfl_xor(s, off, 64);
  return s;
}
__device__ __forceinline__ float wave_reduce_max(float s) {
#pragma unroll
  for (int off = 32; off > 0; off >>= 1) s = fmaxf(s, __shfl_xor(s, off, 64));
  return s;
}

// async 16B global->LDS (linear LDS dest: uniform base + lane*16)
__device__ __forceinline__ void gl16(const void* g, void* l) {
  __builtin_amdgcn_global_load_lds(
      (const __attribute__((address_space(1))) unsigned int*)g,
      (__attribute__((address_space(3))) unsigned int*)l, 16, 0, 0);
}

// ---------------------------------------------------------------- init
__global__ __launch_bounds__(256) void init_kernel(float* __restrict__ accum,
                                                   unsigned int* __restrict__ flags,
                                                   unsigned int* __restrict__ maxbits,
                                                   float* __restrict__ loss) {
  int i = blockIdx.x * 256 + threadIdx.x;
  if (i < ACC_TOTAL) accum[i] = 0.0f;
  if (i < SINK_BLOCKS * FLAG_STRIDE) flags[i] = 0u;
  if (i == 0) { *maxbits = 0u; *loss = 0.0f; }
}

// ---------------------------------------------------------------- convert pass
// fp32 -> {hi,lo} truncated-bf16 split, row-major, plus fused row sum-of-squares.
// One wave per row (512 floats): lane handles 8 consecutive floats.
__global__ __launch_bounds__(256) void convert_kernel(const float* __restrict__ X,
                                                      const float* __restrict__ P,
                                                      unsigned short* __restrict__ Xh,
                                                      unsigned short* __restrict__ Xl,
                                                      unsigned short* __restrict__ Ph,
                                                      unsigned short* __restrict__ Pl,
                                                      float* __restrict__ xn,
                                                      float* __restrict__ pn) {
  const int gw = (blockIdx.x * 256 + threadIdx.x) >> 6;  // global wave id = row id
  const int lane = threadIdx.x & 63;

  const float* src;
  unsigned short *dh, *dl;
  float* nrm;
  if (gw < N_PTS) {
    src = X + (size_t)gw * D_DIM;
    dh = Xh + (size_t)gw * D_DIM;
    dl = Xl + (size_t)gw * D_DIM;
    nrm = xn + gw;
  } else {
    int r = gw - N_PTS;
    src = P + (size_t)r * D_DIM;
    dh = Ph + (size_t)r * D_DIM;
    dl = Pl + (size_t)r * D_DIM;
    nrm = pn + r;
  }

  float4 f0 = *(const float4*)(src + lane * 8);
  float4 f1 = *(const float4*)(src + lane * 8 + 4);
  float f[8] = {f0.x, f0.y, f0.z, f0.w, f1.x, f1.y, f1.z, f1.w};

  float s = 0.f;
#pragma unroll
  for (int j = 0; j < 8; j++) s += f[j] * f[j];

  unsigned int hu[4], lu[4];
#pragma unroll
  for (int j = 0; j < 4; j++) {
    unsigned int a0 = __float_as_uint(f[2 * j]), a1 = __float_as_uint(f[2 * j + 1]);
    hu[j] = __builtin_amdgcn_perm(a1, a0, 0x07060302u);
    unsigned int l0 = __float_as_uint(f[2 * j]     - __uint_as_float(a0 & 0xffff0000u));
    unsigned int l1 = __float_as_uint(f[2 * j + 1] - __uint_as_float(a1 & 0xffff0000u));
    lu[j] = __builtin_amdgcn_perm(l1, l0, 0x07060302u);
  }
  *(uint4*)(dh + lane * 8) = make_uint4(hu[0], hu[1], hu[2], hu[3]);
  *(uint4*)(dl + lane * 8) = make_uint4(lu[0], lu[1], lu[2], lu[3]);

  s = wave_reduce_sum(s);
  if (lane == 0) *nrm = s;
}

// ---------------------------------------------------------------- fast GEMM (pre-split bf16)
// C(fp16) = |x|^2 + |p|^2 - 2*x@p^T via 3-term split-bf16 MFMA.
// 128x128 tile, BK=64 halfs, 4 tiles staged via global_load_lds dwordx4.
// T2 XOR-swizzle: linear LDS dest + pre-swizzled per-lane GLOBAL source + same XOR on ds_read.
__global__ __launch_bounds__(256, 2) void gemm2_kernel(const unsigned short* __restrict__ Xh,
                                                       const unsigned short* __restrict__ Xl,
                                                       const unsigned short* __restrict__ Ph,
                                                       const unsigned short* __restrict__ Pl,
                                                       const float* __restrict__ xn,
                                                       const float* __restrict__ pn,
                                                       __half* __restrict__ Ch,
                                                       unsigned int* __restrict__ maxbits) {
  __shared__ __align__(16) unsigned short Ah[128 * 64];  // 16 KB each
  __shared__ __align__(16) unsigned short Al[128 * 64];
  __shared__ __align__(16) unsigned short Bh[128 * 64];
  __shared__ __align__(16) unsigned short Bl[128 * 64];
  __shared__ float wmax[4];

  const int tid = threadIdx.x;
  const int lane = tid & 63, wv = tid >> 6;
  const int wm = wv >> 1, wn = wv & 1;
  const int m0 = blockIdx.y * 128, k0 = blockIdx.x * 128;

  // staging geometry: chunk = wv*4+is covers rows [chunk*8, chunk*8+8), 8 lanes/row.
  // row&7 == lane>>3 for every chunk; granule g == lane&7; swizzled source granule = g^(row&7).
  const int srow = lane >> 3;                       // row within 8-row chunk
  const int sswg = ((lane & 7) ^ srow) << 4;        // swizzled granule byte offset (const)
  const char* gAh = (const char*)(Xh + (size_t)m0 * D_DIM);
  const char* gAl = (const char*)(Xl + (size_t)m0 * D_DIM);
  const char* gBh = (const char*)(Ph + (size_t)k0 * D_DIM);
  const char* gBl = (const char*)(Pl + (size_t)k0 * D_DIM);

  f32x4 acc[4][4] = {};

  for (int d0 = 0; d0 < D_DIM; d0 += 64) {
    if (d0) __syncthreads();  // previous iteration's fragment reads must finish
#pragma unroll
    for (int is = 0; is < 4; is++) {
      const int chunk = wv * 4 + is;
      const size_t rb = (size_t)(chunk * 8 + srow) * (D_DIM * 2) + (size_t)d0 * 2 + sswg;
      gl16(gAh + rb, &Ah[chunk * 512]);
      gl16(gAl + rb, &Al[chunk * 512]);
      gl16(gBh + rb, &Bh[chunk * 512]);
      gl16(gBl + rb, &Bl[chunk * 512]);
    }
    __syncthreads();  // compiler drains vmcnt(0) before s_barrier

    // B fragments for both k-subtiles
    s16x8 bh[2][4], bl[2][4];
#pragma unroll
    for (int ks = 0; ks < 2; ks++)
#pragma unroll
      for (int ni = 0; ni < 4; ni++) {
        int rB = wn * 64 + ni * 16 + (lane & 15);
        int g = (ks * 4 + (lane >> 4)) ^ (rB & 7);
        bh[ks][ni] = *(const s16x8*)&Bh[rB * 64 + g * 8];
        bl[ks][ni] = *(const s16x8*)&Bl[rB * 64 + g * 8];
      }
#pragma unroll
    for (int mi = 0; mi < 4; mi++) {
      int rA = wm * 64 + mi * 16 + (lane & 15);
      int g0 = (0 + (lane >> 4)) ^ (rA & 7);
      int g1 = (4 + (lane >> 4)) ^ (rA & 7);
      s16x8 a0h = *(const s16x8*)&Ah[rA * 64 + g0 * 8];
      s16x8 a1h = *(const s16x8*)&Ah[rA * 64 + g1 * 8];
      s16x8 a0l = *(const s16x8*)&Al[rA * 64 + g0 * 8];
      s16x8 a1l = *(const s16x8*)&Al[rA * 64 + g1 * 8];
#pragma unroll
      for (int ni = 0; ni < 4; ni++) {
        acc[mi][ni] = __builtin_amdgcn_mfma_f32_16x16x32_bf16(a0h, bh[0][ni], acc[mi][ni], 0, 0, 0);
        acc[mi][ni] = __builtin_amdgcn_mfma_f32_16x16x32_bf16(a1h, bh[1][ni], acc[mi][ni], 0, 0, 0);
        acc[mi][ni] = __builtin_amdgcn_mfma_f32_16x16x32_bf16(a0h, bl[0][ni], acc[mi][ni], 0, 0, 0);
        acc[mi][ni] = __builtin_amdgcn_mfma_f32_16x16x32_bf16(a1h, bl[1][ni], acc[mi][ni], 0, 0, 0);
        acc[mi][ni] = __builtin_amdgcn_mfma_f32_16x16x32_bf16(a0l, bh[0][ni], acc[mi][ni], 0, 0, 0);
        acc[mi][ni] = __builtin_amdgcn_mfma_f32_16x16x32_bf16(a1l, bh[1][ni], acc[mi][ni], 0, 0, 0);
      }
    }
  }

  // epilogue: C/D layout col=lane&15, row=(lane>>4)*4+reg; norms from convert pass
  float lmax = -3.4e38f;
#pragma unroll
  for (int mi = 0; mi < 4; mi++) {
    int rloc = wm * 64 + mi * 16 + (lane >> 4) * 4;
    float dxv[4];
#pragma unroll
    for (int r = 0; r < 4; r++) dxv[r] = xn[m0 + rloc + r];
#pragma unroll
    for (int ni = 0; ni < 4; ni++) {
      int cloc = wn * 64 + ni * 16 + (lane & 15);
      float pnc = pn[k0 + cloc];
#pragma unroll
      for (int r = 0; r < 4; r++) {
        float val = dxv[r] + pnc - 2.0f * acc[mi][ni][r];
        Ch[(size_t)(m0 + rloc + r) * K_PTS + k0 + cloc] = __float2half(val);
        lmax = fmaxf(lmax, val);
      }
    }
  }
  lmax = wave_reduce_max(lmax);
  if (lane == 0) wmax[wv] = lmax;
  __syncthreads();
  if (tid == 0) {
    float m = fmaxf(fmaxf(wmax[0], wmax[1]), fmaxf(wmax[2], wmax[3]));
    atomicMax((int*)maxbits, __float_as_int(m));  // global max is positive
  }
}

// ---------------------------------------------------------------- fallback GEMM (proven path)
// Used only if ws_size can't hold Ph/Pl/xn/pn (+accum/flags) ~2.86 MB.
__global__ __launch_bounds__(256) void gemm_kernel(const float* __restrict__ X,
                                                   const float* __restrict__ P,
                                                   __half* __restrict__ Ch,
                                                   unsigned int* __restrict__ maxbits) {
  __shared__ __align__(16) unsigned short Ah[128 * 32];
  __shared__ __align__(16) unsigned short Al[128 * 32];
  __shared__ __align__(16) unsigned short Bh[128 * 32];
  __shared__ __align__(16) unsigned short Bl[128 * 32];
  __shared__ float dxs[128];
  __shared__ float pns[128];

  const int tid = threadIdx.x;
  const int lane = tid & 63, wv = tid >> 6;
  const int wm = wv >> 1, wn = wv & 1;
  const int m0 = blockIdx.y * 128, k0 = blockIdx.x * 128;
  const int lrow = tid >> 1, lhalf = tid & 1;

  const float* xrow = X + (size_t)(m0 + lrow) * D_DIM + lhalf * 16;
  const float* prow = P + (size_t)(k0 + lrow) * D_DIM + lhalf * 16;
  const int sw = (lrow >> 1) & 3;
  const int woff0 = lrow * 32 + ((2 * lhalf + 0) ^ sw) * 8;
  const int woff1 = lrow * 32 + ((2 * lhalf + 1) ^ sw) * 8;

  f32x4 acc[4][4] = {};
  float sx = 0.f, sp = 0.f;

  for (int d0 = 0; d0 < D_DIM; d0 += 32) {
    float av[16], bv[16];
    {
      const float4* xp = (const float4*)(xrow + d0);
      const float4* pp = (const float4*)(prow + d0);
#pragma unroll
      for (int q = 0; q < 4; q++) {
        float4 a = xp[q], b = pp[q];
        av[q*4+0]=a.x; av[q*4+1]=a.y; av[q*4+2]=a.z; av[q*4+3]=a.w;
        bv[q*4+0]=b.x; bv[q*4+1]=b.y; bv[q*4+2]=b.z; bv[q*4+3]=b.w;
      }
    }
#pragma unroll
    for (int q = 0; q < 16; q++) { sx += av[q] * av[q]; sp += bv[q] * bv[q]; }
    unsigned int ahu[8], alu[8], bhu[8], blu[8];
#pragma unroll
    for (int j = 0; j < 8; j++) {
      unsigned int a0 = __float_as_uint(av[2*j]), a1 = __float_as_uint(av[2*j+1]);
      ahu[j] = __builtin_amdgcn_perm(a1, a0, 0x07060302u);
      unsigned int l0 = __float_as_uint(av[2*j]   - __uint_as_float(a0 & 0xffff0000u));
      unsigned int l1 = __float_as_uint(av[2*j+1] - __uint_as_float(a1 & 0xffff0000u));
      alu[j] = __builtin_amdgcn_perm(l1, l0, 0x07060302u);
      unsigned int b0 = __float_as_uint(bv[2*j]), b1 = __float_as_uint(bv[2*j+1]);
      bhu[j] = __builtin_amdgcn_perm(b1, b0, 0x07060302u);
      unsigned int m0u = __float_as_uint(bv[2*j]   - __uint_as_float(b0 & 0xffff0000u));
      unsigned int m1u = __float_as_uint(bv[2*j+1] - __uint_as_float(b1 & 0xffff0000u));
      blu[j] = __builtin_amdgcn_perm(m1u, m0u, 0x07060302u);
    }
    __syncthreads();
    *(uint4*)&Ah[woff0] = make_uint4(ahu[0], ahu[1], ahu[2], ahu[3]);
    *(uint4*)&Ah[woff1] = make_uint4(ahu[4], ahu[5], ahu[6], ahu[7]);
    *(uint4*)&Al[woff0] = make_uint4(alu[0], alu[1], alu[2], alu[3]);
    *(uint4*)&Al[woff1] = make_uint4(alu[4], alu[5], alu[6], alu[7]);
    *(uint4*)&Bh[woff0] = make_uint4(bhu[0], bhu[1], bhu[2], bhu[3]);
    *(uint4*)&Bh[woff1] = make_uint4(bhu[4], bhu[5], bhu[6], bhu[7]);
    *(uint4*)&Bl[woff0] = make_uint4(blu[0], blu[1], blu[2], blu[3]);
    *(uint4*)&Bl[woff1] = make_uint4(blu[4], blu[5], blu[6], blu[7]);
    __syncthreads();

    s16x8 ah[4], al[4], bh[4], bl[4];
#pragma unroll
    for (int i = 0; i < 4; i++) {
      int rA = wm * 64 + i * 16 + (lane & 15);
      int gA = (lane >> 4) ^ ((rA >> 1) & 3);
      ah[i] = *(const s16x8*)&Ah[rA * 32 + gA * 8];
      al[i] = *(const s16x8*)&Al[rA * 32 + gA * 8];
      int rB = wn * 64 + i * 16 + (lane & 15);
      int gB = (lane >> 4) ^ ((rB >> 1) & 3);
      bh[i] = *(const s16x8*)&Bh[rB * 32 + gB * 8];
      bl[i] = *(const s16x8*)&Bl[rB * 32 + gB * 8];
    }
#pragma unroll
    for (int mi = 0; mi < 4; mi++)
#pragma unroll
      for (int ni = 0; ni < 4; ni++) {
        acc[mi][ni] = __builtin_amdgcn_mfma_f32_16x16x32_bf16(ah[mi], bh[ni], acc[mi][ni], 0, 0, 0);
        acc[mi][ni] = __builtin_amdgcn_mfma_f32_16x16x32_bf16(ah[mi], bl[ni], acc[mi][ni], 0, 0, 0);
        acc[mi][ni] = __builtin_amdgcn_mfma_f32_16x16x32_bf16(al[mi], bh[ni], acc[mi][ni], 0, 0, 0);
      }
  }

  float px = sx + __shfl_xor(sx, 1, 64);
  float pp2 = sp + __shfl_xor(sp, 1, 64);
  __syncthreads();
  dxs[lrow] = px;
  pns[lrow] = pp2;
  __syncthreads();

  float lmax = -3.4e38f;
#pragma unroll
  for (int mi = 0; mi < 4; mi++) {
    int rloc = wm * 64 + mi * 16 + (lane >> 4) * 4;
    float dxv[4];
#pragma unroll
    for (int r = 0; r < 4; r++) dxv[r] = dxs[rloc + r];
#pragma unroll
    for (int ni = 0; ni < 4; ni++) {
      int cloc = wn * 64 + ni * 16 + (lane & 15);
      float pnc = pns[cloc];
#pragma unroll
      for (int r = 0; r < 4; r++) {
        float val = dxv[r] + pnc - 2.0f * acc[mi][ni][r];
        Ch[(size_t)(m0 + rloc + r) * K_PTS + k0 + cloc] = __float2half(val);
        lmax = fmaxf(lmax, val);
      }
    }
  }
  lmax = wave_reduce_max(lmax);
  __shared__ float wmax[4];
  if (lane == 0) wmax[wv] = lmax;
  __syncthreads();
  if (tid == 0) {
    float m = fmaxf(fmaxf(wmax[0], wmax[1]), fmaxf(wmax[2], wmax[3]));
    atomicMax((int*)maxbits, __float_as_int(m));
  }
}

// ---------------------------------------------------------------- persistent Sinkhorn, fully fused
// (unchanged from verified version)
__global__ __launch_bounds__(512, 2) void sinkhorn_kernel(
    const __half* __restrict__ Ch,
    const unsigned int* __restrict__ maxbits,
    float* __restrict__ accum,          // (ITERS+1) x NCOPY x K_PTS
    unsigned int* __restrict__ flags,   // SINK_BLOCKS x FLAG_STRIDE
    float* __restrict__ T,
    float* __restrict__ loss) {
  __shared__ float v_lds[K_PTS];
  __shared__ float red[8][K_PTS];
  const int tid = threadIdx.x;
  const int lane = tid & 63, wv = tid >> 6;
  const int b = blockIdx.x;
  const int r0 = b * 64 + wv * 8;

  float factor;
  {
    float cmax = __int_as_float((int)*maxbits);
    factor = -1.0f / ((cmax + 1e-8f) * EPS_F);
  }
  f32x4 k4[32];
#pragma unroll
  for (int i = 0; i < 8; i++) {
    const __half* rp = Ch + (size_t)(r0 + i) * K_PTS + lane;
#pragma unroll
    for (int q = 0; q < 4; q++) {
      f32x4 kk;
#pragma unroll
      for (int e = 0; e < 4; e++)
        kk[e] = __expf(__half2float(rp[(4 * q + e) * 64]) * factor);
      k4[i * 4 + q] = kk;
    }
  }
  v_lds[tid * 2 + 0] = 1.0f;
  v_lds[tid * 2 + 1] = 1.0f;
  __syncthreads();

  float su[8];
  for (int t = 0; t < ITERS; t++) {
    f32x4 vr4[4];
#pragma unroll
    for (int q = 0; q < 4; q++)
#pragma unroll
      for (int e = 0; e < 4; e++)
        vr4[q][e] = v_lds[(4 * q + e) * 64 + lane];

    float s[8];
#pragma unroll
    for (int i = 0; i < 8; i++) {
      f32x4 d = k4[i * 4 + 0] * vr4[0] + k4[i * 4 + 1] * vr4[1]
              + k4[i * 4 + 2] * vr4[2] + k4[i * 4 + 3] * vr4[3];
      s[i] = d[0] + d[1] + d[2] + d[3];
    }
    {
      const bool h32 = (lane & 32) != 0;
      float a[4];
#pragma unroll
      for (int i = 0; i < 4; i++) {
        float x = h32 ? s[i] : s[i + 4];
        float y = h32 ? s[i + 4] : s[i];
        a[i] = y + __shfl_xor(x, 32, 64);
      }
      const bool h16 = (lane & 16) != 0;
      float c[2];
#pragma unroll
      for (int i = 0; i < 2; i++) {
        float x = h16 ? a[i] : a[i + 2];
        float y = h16 ? a[i + 2] : a[i];
        c[i] = y + __shfl_xor(x, 16, 64);
      }
      const bool h8 = (lane & 8) != 0;
      float x = h8 ? c[0] : c[1];
      float y = h8 ? c[1] : c[0];
      float w = y + __shfl_xor(x, 8, 64);
      w += __shfl_xor(w, 4, 64);
      w += __shfl_xor(w, 2, 64);
      w += __shfl_xor(w, 1, 64);
      float ui_local = MU_F / (w + 1e-8f);
#pragma unroll
      for (int i = 0; i < 8; i++)
        su[i] = __uint_as_float(__builtin_amdgcn_readlane(__float_as_uint(ui_local), i * 8));
    }
    f32x4 ca4[4] = {};
#pragma unroll
    for (int i = 0; i < 8; i++)
#pragma unroll
      for (int q = 0; q < 4; q++)
        ca4[q] += su[i] * k4[i * 4 + q];

    __syncthreads();
#pragma unroll
    for (int q = 0; q < 4; q++)
#pragma unroll
      for (int e = 0; e < 4; e++)
        red[wv][(4 * q + e) * 64 + lane] = ca4[q][e];
    __syncthreads();
    {
      float s0 = 0.f, s1 = 0.f;
#pragma unroll
      for (int w8 = 0; w8 < 8; w8++) {
        float2 v2 = *(const float2*)&red[w8][tid * 2];
        s0 += v2.x; s1 += v2.y;
      }
      float* dst = accum + (size_t)(t + 1) * (NCOPY * K_PTS)
                 + (size_t)(b & (NCOPY - 1)) * K_PTS + tid * 2;
      atomicAdd(dst + 0, s0);
      atomicAdd(dst + 1, s1);
    }
    __syncthreads();
    if (tid == 0)
      __hip_atomic_store(&flags[(size_t)b * FLAG_STRIDE], (unsigned)(t + 1),
                         __ATOMIC_RELEASE, __HIP_MEMORY_SCOPE_AGENT);
    if (tid < SINK_BLOCKS) {
      while (__hip_atomic_load(&flags[(size_t)tid * FLAG_STRIDE],
                               __ATOMIC_RELAXED, __HIP_MEMORY_SCOPE_AGENT) < (unsigned)(t + 1))
        __builtin_amdgcn_s_sleep(4);
    }
    __syncthreads();
    {
      float* st = accum + (size_t)(t + 1) * (NCOPY * K_PTS);
      float s0 = 0.f, s1 = 0.f;
#pragma unroll
      for (int c = 0; c < NCOPY; c++) {
        s0 += __hip_atomic_load(st + (size_t)c * K_PTS + tid * 2 + 0,
                                __ATOMIC_RELAXED, __HIP_MEMORY_SCOPE_AGENT);
        s1 += __hip_atomic_load(st + (size_t)c * K_PTS + tid * 2 + 1,
                                __ATOMIC_RELAXED, __HIP_MEMORY_SCOPE_AGENT);
      }
      v_lds[tid * 2 + 0] = NU_F / (s0 + 1e-8f);
      v_lds[tid * 2 + 1] = NU_F / (s1 + 1e-8f);
    }
    __syncthreads();
  }

  float lsum = 0.f;
#pragma unroll
  for (int i = 0; i < 8; i++) {
    float* Trow = T + (size_t)(r0 + i) * K_PTS + lane;
#pragma unroll
    for (int q = 0; q < 4; q++) {
#pragma unroll
      for (int e = 0; e < 4; e++) {
        int c = (4 * q + e) * 64;
        float kk = k4[i * 4 + q][e];
        float tv = su[i] * kk * v_lds[c + lane];
        Trow[c] = tv;
        lsum += tv * (-EPS_F * __logf(kk));
      }
    }
  }
  lsum = wave_reduce_sum(lsum);
  __shared__ float wsum[8];
  if (lane == 0) wsum[wv] = lsum;
  __syncthreads();
  if (tid == 0) {
    float m = 0.f;
#pragma unroll
    for (int i = 0; i < 8; i++) m += wsum[i];
    atomicAdd(loss, m);
  }
}

// ---------------------------------------------------------------- launcher
extern "C" void kernel_launch(void* const* d_in, const int* in_sizes, int n_in,
                              void* d_out, int out_size, void* d_ws, size_t ws_size,
                              hipStream_t stream) {
  const float* x = (const float*)d_in[0];
  const float* p = (const float*)d_in[1];
  float* T = (float*)d_out;
  float* loss = (float*)d_out + (size_t)N_PTS * K_PTS;
  __half* Ch = (__half*)d_out;  // fp16 C staged in d_out[0, 32MiB)

  // X splits live in d_out's upper half (dead until sinkhorn's final T write)
  unsigned short* Xh = (unsigned short*)((char*)d_out + ((size_t)32 << 20));
  unsigned short* Xl = (unsigned short*)((char*)d_out + ((size_t)48 << 20));

  char* wsb = (char*)d_ws;
  size_t off = 0;
  float* accum = (float*)(wsb + off);                 off += WS_ACCUM_BYTES;
  unsigned int* flags = (unsigned int*)(wsb + off);   off += WS_FLAGS_BYTES;
  unsigned int* maxbits = (unsigned int*)(wsb + off); off += WS_MAX_BYTES;
  float* xn = (float*)(wsb + off);                    off += WS_XN_BYTES;
  float* pn = (float*)(wsb + off);                    off += WS_PN_BYTES;
  unsigned short* Ph = (unsigned short*)(wsb + off);  off += WS_PH_BYTES;
  unsigned short* Pl = (unsigned short*)(wsb + off);  off += WS_PH_BYTES;
  const size_t ws_need_fast = off;   // ~2.86 MB

  init_kernel<<<(ACC_TOTAL + 255) / 256, 256, 0, stream>>>(accum, flags, maxbits, loss);
  if (ws_size >= ws_need_fast) {
    convert_kernel<<<(N_PTS + K_PTS) / 4, 256, 0, stream>>>(x, p, Xh, Xl, Ph, Pl, xn, pn);
    gemm2_kernel<<<dim3(K_PTS / 128, N_PTS / 128), 256, 0, stream>>>(Xh, Xl, Ph, Pl, xn, pn, Ch, maxbits);
  } else {
    gemm_kernel<<<dim3(K_PTS / 128, N_PTS / 128), 256, 0, stream>>>(x, p, Ch, maxbits);
  }
  sinkhorn_kernel<<<SINK_BLOCKS, 512, 0, stream>>>(Ch, maxbits, accum, flags, T, loss);
}

// Round 3
// 300.990 us; speedup vs baseline: 1.1220x; 1.0819x over previous
//
#include <hip/hip_runtime.h>
#include <hip/hip_fp16.h>
#include <cstddef>
#include <cstdint>

#define N_PTS 16384
#define K_PTS 1024
#define D_DIM 512
#define EPS_F 0.1f
#define ITERS 20
#define MU_F (1.0f/16384.0f)
#define NU_F (1.0f/1024.0f)
#define NCOPY 8
#define SINK_BLOCKS 256
#define FLAG_STRIDE 16   // 64B padding per flag
#define ACC_TOTAL ((ITERS + 1) * NCOPY * K_PTS)

// workspace layout (bytes) — ONLY the proven footprint (~0.67 MB), no conditionals
#define WS_ACCUM_BYTES ((size_t)ACC_TOTAL * 4)                    // 688128
#define WS_FLAGS_BYTES ((size_t)SINK_BLOCKS * FLAG_STRIDE * 4)    // 16384

// d_out layout (64 MiB + 4 B):
//   [0,        32 MiB)  Ch    (fp16 C, staged between gemm and sinkhorn)
//   [32 MiB,   48 MiB)  Xf16  (f16 X, 16384x512)
//   [48 MiB,   49 MiB)  Pf16  (f16 P, 1024x512)
//   [49 MiB,  +64 KiB)  xn    (f32 row norms of X)
//   then       +4 KiB)  pn    (f32 row norms of P)
//   [64 MiB]            loss
// All regions are read before sinkhorn's final T writes clobber them
// (each sinkhorn block reads Ch rows it later writes as T; Xf16/Pf16/xn/pn
//  are only read by gemm3 which completes before sinkhorn launches).

typedef float f32x4 __attribute__((ext_vector_type(4)));
typedef _Float16 f16x8 __attribute__((ext_vector_type(8)));

__device__ __forceinline__ float wave_reduce_sum(float s) {
#pragma unroll
  for (int off = 32; off > 0; off >>= 1) s += __shfl_xor(s, off, 64);
  return s;
}
__device__ __forceinline__ float wave_reduce_max(float s) {
#pragma unroll
  for (int off = 32; off > 0; off >>= 1) s = fmaxf(s, __shfl_xor(s, off, 64));
  return s;
}

// async 16B global->LDS (linear LDS dest: wave-uniform base + lane*16)
__device__ __forceinline__ void gl16(const void* g, void* l) {
  __builtin_amdgcn_global_load_lds(
      (const __attribute__((address_space(1))) unsigned int*)g,
      (__attribute__((address_space(3))) unsigned int*)l, 16, 0, 0);
}

// ---------------------------------------------------------------- init
__global__ __launch_bounds__(256) void init_kernel(float* __restrict__ accum,
                                                   unsigned int* __restrict__ flags,
                                                   unsigned int* __restrict__ maxbits,
                                                   float* __restrict__ loss) {
  int i = blockIdx.x * 256 + threadIdx.x;
  if (i < ACC_TOTAL) accum[i] = 0.0f;
  if (i < SINK_BLOCKS * FLAG_STRIDE) flags[i] = 0u;
  if (i == 0) { *maxbits = 0u; *loss = 0.0f; }
}

// ---------------------------------------------------------------- convert pass
// fp32 -> f16 (RTN), row-major, plus fused exact-f32 row sum-of-squares.
// One wave per row (512 floats): lane handles 8 consecutive floats.
__global__ __launch_bounds__(256) void convert_kernel(const float* __restrict__ X,
                                                      const float* __restrict__ P,
                                                      unsigned short* __restrict__ Xf,
                                                      unsigned short* __restrict__ Pf,
                                                      float* __restrict__ xn,
                                                      float* __restrict__ pn) {
  const int gw = (blockIdx.x * 256 + threadIdx.x) >> 6;  // global wave id = row id
  const int lane = threadIdx.x & 63;

  const float* src;
  unsigned short* dst;
  float* nrm;
  if (gw < N_PTS) {
    src = X + (size_t)gw * D_DIM;
    dst = Xf + (size_t)gw * D_DIM;
    nrm = xn + gw;
  } else {
    int r = gw - N_PTS;
    src = P + (size_t)r * D_DIM;
    dst = Pf + (size_t)r * D_DIM;
    nrm = pn + r;
  }

  float4 f0 = *(const float4*)(src + lane * 8);
  float4 f1 = *(const float4*)(src + lane * 8 + 4);
  float f[8] = {f0.x, f0.y, f0.z, f0.w, f1.x, f1.y, f1.z, f1.w};

  float s = 0.f;
#pragma unroll
  for (int j = 0; j < 8; j++) s += f[j] * f[j];

  unsigned int u[4];
#pragma unroll
  for (int j = 0; j < 4; j++) {
    unsigned int lo = (unsigned int)__half_as_ushort(__float2half(f[2 * j]));
    unsigned int hi = (unsigned int)__half_as_ushort(__float2half(f[2 * j + 1]));
    u[j] = lo | (hi << 16);
  }
  *(uint4*)(dst + lane * 8) = make_uint4(u[0], u[1], u[2], u[3]);

  s = wave_reduce_sum(s);
  if (lane == 0) *nrm = s;
}

// ---------------------------------------------------------------- f16 MFMA GEMM
// C(fp16) = |x|^2 + |p|^2 - 2*x@p^T, single f16 MFMA term (input-rounding error
// std ~0.009 abs, 15x below the fp16-C storage noise already present).
// 128x128 tile, BK=64 halfs, staged via global_load_lds dwordx4.
// Granule XOR-swizzle: linear LDS dest + pre-swizzled per-lane GLOBAL source
// + same XOR on ds_read (both-sides-or-neither, rule #21). Conflict-free.
__global__ __launch_bounds__(256, 2) void gemm3_kernel(const unsigned short* __restrict__ Xf,
                                                       const unsigned short* __restrict__ Pf,
                                                       const float* __restrict__ xn,
                                                       const float* __restrict__ pn,
                                                       __half* __restrict__ Ch,
                                                       unsigned int* __restrict__ maxbits) {
  __shared__ __align__(16) unsigned short Af[128 * 64];  // 16 KB
  __shared__ __align__(16) unsigned short Bf[128 * 64];  // 16 KB
  __shared__ float wmax[4];

  const int tid = threadIdx.x;
  const int lane = tid & 63, wv = tid >> 6;
  const int wm = wv >> 1, wn = wv & 1;
  const int m0 = blockIdx.y * 128, k0 = blockIdx.x * 128;

  // staging geometry: chunk covers rows [chunk*8, chunk*8+8), 8 lanes/row.
  // srow = lane>>3 (row in chunk); granule slot g = lane&7 holds source granule g^srow.
  const int srow = lane >> 3;
  const int sswg = ((lane & 7) ^ srow) << 4;        // swizzled source granule byte offset
  const char* gA = (const char*)(Xf + (size_t)m0 * D_DIM);
  const char* gB = (const char*)(Pf + (size_t)k0 * D_DIM);

  f32x4 acc[4][4] = {};

  for (int d0 = 0; d0 < D_DIM; d0 += 64) {
    if (d0) __syncthreads();  // previous iteration's fragment reads must finish
#pragma unroll
    for (int is = 0; is < 4; is++) {
      const int chunk = wv * 4 + is;                // 16 chunks cover 128 rows
      const size_t rb = (size_t)(chunk * 8 + srow) * (D_DIM * 2) + (size_t)d0 * 2 + sswg;
      gl16(gA + rb, &Af[chunk * 512]);
      gl16(gB + rb, &Bf[chunk * 512]);
    }
    __syncthreads();  // drains vmcnt(0) before barrier

    // fragments: row r, k-granule j at LDS slot j^(r&7)
    f16x8 av[2][4], bv[2][4];
#pragma unroll
    for (int ks = 0; ks < 2; ks++)
#pragma unroll
      for (int i = 0; i < 4; i++) {
        int rA = wm * 64 + i * 16 + (lane & 15);
        int gAi = (ks * 4 + (lane >> 4)) ^ (rA & 7);
        av[ks][i] = *(const f16x8*)&Af[rA * 64 + gAi * 8];
        int rB = wn * 64 + i * 16 + (lane & 15);
        int gBi = (ks * 4 + (lane >> 4)) ^ (rB & 7);
        bv[ks][i] = *(const f16x8*)&Bf[rB * 64 + gBi * 8];
      }
#pragma unroll
    for (int mi = 0; mi < 4; mi++)
#pragma unroll
      for (int ni = 0; ni < 4; ni++) {
        acc[mi][ni] = __builtin_amdgcn_mfma_f32_16x16x32_f16(av[0][mi], bv[0][ni], acc[mi][ni], 0, 0, 0);
        acc[mi][ni] = __builtin_amdgcn_mfma_f32_16x16x32_f16(av[1][mi], bv[1][ni], acc[mi][ni], 0, 0, 0);
      }
  }

  // epilogue: C/D layout col=lane&15, row=(lane>>4)*4+reg; norms from convert pass
  float lmax = -3.4e38f;
#pragma unroll
  for (int mi = 0; mi < 4; mi++) {
    int rloc = wm * 64 + mi * 16 + (lane >> 4) * 4;
    float dxv[4];
#pragma unroll
    for (int r = 0; r < 4; r++) dxv[r] = xn[m0 + rloc + r];
#pragma unroll
    for (int ni = 0; ni < 4; ni++) {
      int cloc = wn * 64 + ni * 16 + (lane & 15);
      float pnc = pn[k0 + cloc];
#pragma unroll
      for (int r = 0; r < 4; r++) {
        float val = dxv[r] + pnc - 2.0f * acc[mi][ni][r];
        Ch[(size_t)(m0 + rloc + r) * K_PTS + k0 + cloc] = __float2half(val);
        lmax = fmaxf(lmax, val);
      }
    }
  }
  lmax = wave_reduce_max(lmax);
  if (lane == 0) wmax[wv] = lmax;
  __syncthreads();
  if (tid == 0) {
    float m = fmaxf(fmaxf(wmax[0], wmax[1]), fmaxf(wmax[2], wmax[3]));
    atomicMax((int*)maxbits, __float_as_int(m));  // global max is positive
  }
}

// ---------------------------------------------------------------- persistent Sinkhorn, fully fused
// (unchanged from verified version)
__global__ __launch_bounds__(512, 2) void sinkhorn_kernel(
    const __half* __restrict__ Ch,
    const unsigned int* __restrict__ maxbits,
    float* __restrict__ accum,          // (ITERS+1) x NCOPY x K_PTS
    unsigned int* __restrict__ flags,   // SINK_BLOCKS x FLAG_STRIDE
    float* __restrict__ T,
    float* __restrict__ loss) {
  __shared__ float v_lds[K_PTS];
  __shared__ float red[8][K_PTS];
  const int tid = threadIdx.x;
  const int lane = tid & 63, wv = tid >> 6;
  const int b = blockIdx.x;
  const int r0 = b * 64 + wv * 8;

  float factor;
  {
    float cmax = __int_as_float((int)*maxbits);
    factor = -1.0f / ((cmax + 1e-8f) * EPS_F);
  }
  f32x4 k4[32];
#pragma unroll
  for (int i = 0; i < 8; i++) {
    const __half* rp = Ch + (size_t)(r0 + i) * K_PTS + lane;
#pragma unroll
    for (int q = 0; q < 4; q++) {
      f32x4 kk;
#pragma unroll
      for (int e = 0; e < 4; e++)
        kk[e] = __expf(__half2float(rp[(4 * q + e) * 64]) * factor);
      k4[i * 4 + q] = kk;
    }
  }
  v_lds[tid * 2 + 0] = 1.0f;
  v_lds[tid * 2 + 1] = 1.0f;
  __syncthreads();

  float su[8];
  for (int t = 0; t < ITERS; t++) {
    f32x4 vr4[4];
#pragma unroll
    for (int q = 0; q < 4; q++)
#pragma unroll
      for (int e = 0; e < 4; e++)
        vr4[q][e] = v_lds[(4 * q + e) * 64 + lane];

    float s[8];
#pragma unroll
    for (int i = 0; i < 8; i++) {
      f32x4 d = k4[i * 4 + 0] * vr4[0] + k4[i * 4 + 1] * vr4[1]
              + k4[i * 4 + 2] * vr4[2] + k4[i * 4 + 3] * vr4[3];
      s[i] = d[0] + d[1] + d[2] + d[3];
    }
    {
      const bool h32 = (lane & 32) != 0;
      float a[4];
#pragma unroll
      for (int i = 0; i < 4; i++) {
        float x = h32 ? s[i] : s[i + 4];
        float y = h32 ? s[i + 4] : s[i];
        a[i] = y + __shfl_xor(x, 32, 64);
      }
      const bool h16 = (lane & 16) != 0;
      float c[2];
#pragma unroll
      for (int i = 0; i < 2; i++) {
        float x = h16 ? a[i] : a[i + 2];
        float y = h16 ? a[i + 2] : a[i];
        c[i] = y + __shfl_xor(x, 16, 64);
      }
      const bool h8 = (lane & 8) != 0;
      float x = h8 ? c[0] : c[1];
      float y = h8 ? c[1] : c[0];
      float w = y + __shfl_xor(x, 8, 64);
      w += __shfl_xor(w, 4, 64);
      w += __shfl_xor(w, 2, 64);
      w += __shfl_xor(w, 1, 64);
      float ui_local = MU_F / (w + 1e-8f);
#pragma unroll
      for (int i = 0; i < 8; i++)
        su[i] = __uint_as_float(__builtin_amdgcn_readlane(__float_as_uint(ui_local), i * 8));
    }
    f32x4 ca4[4] = {};
#pragma unroll
    for (int i = 0; i < 8; i++)
#pragma unroll
      for (int q = 0; q < 4; q++)
        ca4[q] += su[i] * k4[i * 4 + q];

    __syncthreads();
#pragma unroll
    for (int q = 0; q < 4; q++)
#pragma unroll
      for (int e = 0; e < 4; e++)
        red[wv][(4 * q + e) * 64 + lane] = ca4[q][e];
    __syncthreads();
    {
      float s0 = 0.f, s1 = 0.f;
#pragma unroll
      for (int w8 = 0; w8 < 8; w8++) {
        float2 v2 = *(const float2*)&red[w8][tid * 2];
        s0 += v2.x; s1 += v2.y;
      }
      float* dst = accum + (size_t)(t + 1) * (NCOPY * K_PTS)
                 + (size_t)(b & (NCOPY - 1)) * K_PTS + tid * 2;
      atomicAdd(dst + 0, s0);
      atomicAdd(dst + 1, s1);
    }
    __syncthreads();
    if (tid == 0)
      __hip_atomic_store(&flags[(size_t)b * FLAG_STRIDE], (unsigned)(t + 1),
                         __ATOMIC_RELEASE, __HIP_MEMORY_SCOPE_AGENT);
    if (tid < SINK_BLOCKS) {
      while (__hip_atomic_load(&flags[(size_t)tid * FLAG_STRIDE],
                               __ATOMIC_RELAXED, __HIP_MEMORY_SCOPE_AGENT) < (unsigned)(t + 1))
        __builtin_amdgcn_s_sleep(4);
    }
    __syncthreads();
    {
      float* st = accum + (size_t)(t + 1) * (NCOPY * K_PTS);
      float s0 = 0.f, s1 = 0.f;
#pragma unroll
      for (int c = 0; c < NCOPY; c++) {  // agent-scope loads bypass stale caches (G16)
        s0 += __hip_atomic_load(st + (size_t)c * K_PTS + tid * 2 + 0,
                                __ATOMIC_RELAXED, __HIP_MEMORY_SCOPE_AGENT);
        s1 += __hip_atomic_load(st + (size_t)c * K_PTS + tid * 2 + 1,
                                __ATOMIC_RELAXED, __HIP_MEMORY_SCOPE_AGENT);
      }
      v_lds[tid * 2 + 0] = NU_F / (s0 + 1e-8f);
      v_lds[tid * 2 + 1] = NU_F / (s1 + 1e-8f);
    }
    __syncthreads();
  }

  float lsum = 0.f;
#pragma unroll
  for (int i = 0; i < 8; i++) {
    float* Trow = T + (size_t)(r0 + i) * K_PTS + lane;
#pragma unroll
    for (int q = 0; q < 4; q++) {
#pragma unroll
      for (int e = 0; e < 4; e++) {
        int c = (4 * q + e) * 64;
        float kk = k4[i * 4 + q][e];
        float tv = su[i] * kk * v_lds[c + lane];
        Trow[c] = tv;
        lsum += tv * (-EPS_F * __logf(kk));
      }
    }
  }
  lsum = wave_reduce_sum(lsum);
  __shared__ float wsum[8];
  if (lane == 0) wsum[wv] = lsum;
  __syncthreads();
  if (tid == 0) {
    float m = 0.f;
#pragma unroll
    for (int i = 0; i < 8; i++) m += wsum[i];
    atomicAdd(loss, m);
  }
}

// ---------------------------------------------------------------- launcher
extern "C" void kernel_launch(void* const* d_in, const int* in_sizes, int n_in,
                              void* d_out, int out_size, void* d_ws, size_t ws_size,
                              hipStream_t stream) {
  const float* x = (const float*)d_in[0];
  const float* p = (const float*)d_in[1];
  float* T = (float*)d_out;
  float* loss = (float*)d_out + (size_t)N_PTS * K_PTS;
  __half* Ch = (__half*)d_out;  // fp16 C staged in d_out[0, 32MiB)

  // f16 operands + norms live in d_out's upper half (dead until sinkhorn's final T write)
  unsigned short* Xf = (unsigned short*)((char*)d_out + ((size_t)32 << 20));
  unsigned short* Pf = (unsigned short*)((char*)d_out + ((size_t)48 << 20));
  float* xn = (float*)((char*)d_out + ((size_t)49 << 20));
  float* pn = xn + N_PTS;

  char* wsb = (char*)d_ws;
  float* accum = (float*)wsb;
  unsigned int* flags = (unsigned int*)(wsb + WS_ACCUM_BYTES);
  unsigned int* maxbits = (unsigned int*)(wsb + WS_ACCUM_BYTES + WS_FLAGS_BYTES);

  init_kernel<<<(ACC_TOTAL + 255) / 256, 256, 0, stream>>>(accum, flags, maxbits, loss);
  convert_kernel<<<(N_PTS + K_PTS) / 4, 256, 0, stream>>>(x, p, Xf, Pf, xn, pn);
  gemm3_kernel<<<dim3(K_PTS / 128, N_PTS / 128), 256, 0, stream>>>(Xf, Pf, xn, pn, Ch, maxbits);
  sinkhorn_kernel<<<SINK_BLOCKS, 512, 0, stream>>>(Ch, maxbits, accum, flags, T, loss);
}

// Round 4
// 299.652 us; speedup vs baseline: 1.1270x; 1.0045x over previous
//
#include <hip/hip_runtime.h>
#include <hip/hip_fp16.h>
#include <cstddef>
#include <cstdint>

#define N_PTS 16384
#define K_PTS 1024
#define D_DIM 512
#define EPS_F 0.1f
#define ITERS 20
#define MU_F (1.0f/16384.0f)
#define NU_F (1.0f/1024.0f)
#define NCOPY 8
#define SINK_BLOCKS 256
#define FLAG_STRIDE 16   // 64B padding per flag
#define ACC_TOTAL ((ITERS + 1) * NCOPY * K_PTS)

// workspace layout (bytes) — ONLY the proven footprint (~0.67 MB), no conditionals
#define WS_ACCUM_BYTES ((size_t)ACC_TOTAL * 4)                    // 688128
#define WS_FLAGS_BYTES ((size_t)SINK_BLOCKS * FLAG_STRIDE * 4)    // 16384

// d_out layout (64 MiB + 4 B):
//   [0,        32 MiB)  Ch    (fp16 C, staged between gemm and sinkhorn)
//   [32 MiB,   48 MiB)  Xf16  (f16 X, 16384x512)
//   [48 MiB,   49 MiB)  Pf16  (f16 P, 1024x512)
//   [49 MiB,  +64 KiB)  xn    (f32 row norms of X)
//   then       +4 KiB)  pn    (f32 row norms of P)
//   [64 MiB]            loss
// All regions are read before sinkhorn's final T writes clobber them.

typedef float f32x4 __attribute__((ext_vector_type(4)));
typedef _Float16 f16x8 __attribute__((ext_vector_type(8)));

__device__ __forceinline__ float wave_reduce_sum(float s) {
#pragma unroll
  for (int off = 32; off > 0; off >>= 1) s += __shfl_xor(s, off, 64);
  return s;
}
__device__ __forceinline__ float wave_reduce_max(float s) {
#pragma unroll
  for (int off = 32; off > 0; off >>= 1) s = fmaxf(s, __shfl_xor(s, off, 64));
  return s;
}

// async 16B global->LDS (linear LDS dest: wave-uniform base + lane*16)
__device__ __forceinline__ void gl16(const void* g, void* l) {
  __builtin_amdgcn_global_load_lds(
      (const __attribute__((address_space(1))) unsigned int*)g,
      (__attribute__((address_space(3))) unsigned int*)l, 16, 0, 0);
}

// ---------------------------------------------------------------- init
__global__ __launch_bounds__(256) void init_kernel(float* __restrict__ accum,
                                                   unsigned int* __restrict__ flags,
                                                   unsigned int* __restrict__ maxbits,
                                                   float* __restrict__ loss) {
  int i = blockIdx.x * 256 + threadIdx.x;
  if (i < ACC_TOTAL) accum[i] = 0.0f;
  if (i < SINK_BLOCKS * FLAG_STRIDE) flags[i] = 0u;
  if (i == 0) { *maxbits = 0u; *loss = 0.0f; }
}

// ---------------------------------------------------------------- convert pass
// fp32 -> f16 (RTN), row-major, plus fused exact-f32 row sum-of-squares.
// One wave per row (512 floats): lane handles 8 consecutive floats.
__global__ __launch_bounds__(256) void convert_kernel(const float* __restrict__ X,
                                                      const float* __restrict__ P,
                                                      unsigned short* __restrict__ Xf,
                                                      unsigned short* __restrict__ Pf,
                                                      float* __restrict__ xn,
                                                      float* __restrict__ pn) {
  const int gw = (blockIdx.x * 256 + threadIdx.x) >> 6;  // global wave id = row id
  const int lane = threadIdx.x & 63;

  const float* src;
  unsigned short* dst;
  float* nrm;
  if (gw < N_PTS) {
    src = X + (size_t)gw * D_DIM;
    dst = Xf + (size_t)gw * D_DIM;
    nrm = xn + gw;
  } else {
    int r = gw - N_PTS;
    src = P + (size_t)r * D_DIM;
    dst = Pf + (size_t)r * D_DIM;
    nrm = pn + r;
  }

  float4 f0 = *(const float4*)(src + lane * 8);
  float4 f1 = *(const float4*)(src + lane * 8 + 4);
  float f[8] = {f0.x, f0.y, f0.z, f0.w, f1.x, f1.y, f1.z, f1.w};

  float s = 0.f;
#pragma unroll
  for (int j = 0; j < 8; j++) s += f[j] * f[j];

  unsigned int u[4];
#pragma unroll
  for (int j = 0; j < 4; j++) {
    unsigned int lo = (unsigned int)__half_as_ushort(__float2half(f[2 * j]));
    unsigned int hi = (unsigned int)__half_as_ushort(__float2half(f[2 * j + 1]));
    u[j] = lo | (hi << 16);
  }
  *(uint4*)(dst + lane * 8) = make_uint4(u[0], u[1], u[2], u[3]);

  s = wave_reduce_sum(s);
  if (lane == 0) *nrm = s;
}

// ---------------------------------------------------------------- f16 MFMA GEMM, v4
// C(fp16) = |x|^2 + |p|^2 - 2*x@p^T, single f16 MFMA term.
// 128x128 tile, BK=64 halfs, 8 K-iters, 2-stage DOUBLE-BUFFERED staging
// (stage t+1 issued before compute t; one __syncthreads per iter drains
// vmcnt and protects buffer reuse — T3-minimum 2-phase).
// Epilogue: fp16 tile transposed through LDS (row stride 272B) and stored
// with dwordx4 — 8 coalesced 16B stores/thread instead of 64 scalar 2B.
#define CT_STRIDE 136   // halfs per epilogue-tile row (272B = 17*16B)

__global__ __launch_bounds__(256, 2) void gemm4_kernel(const unsigned short* __restrict__ Xf,
                                                       const unsigned short* __restrict__ Pf,
                                                       const float* __restrict__ xn,
                                                       const float* __restrict__ pn,
                                                       __half* __restrict__ Ch,
                                                       unsigned int* __restrict__ maxbits) {
  // [buf][A=0/B=1][128*64 halfs]; epilogue C-tile (128*136 halfs = 34,816B) aliases Sh.
  __shared__ __align__(16) unsigned short Sh[2][2][128 * 64];   // 64 KB
  __shared__ float wmax[4];

  const int tid = threadIdx.x;
  const int lane = tid & 63, wv = tid >> 6;
  const int wm = wv >> 1, wn = wv & 1;
  const int m0 = blockIdx.y * 128, k0 = blockIdx.x * 128;

  // staging geometry: chunk covers rows [chunk*8, chunk*8+8), 8 lanes/row.
  // srow = lane>>3 (row in chunk); LDS slot lane&7 receives source granule (lane&7)^srow.
  const int srow = lane >> 3;
  const int sswg = ((lane & 7) ^ srow) << 4;        // swizzled source granule byte offset
  const char* gA = (const char*)(Xf + (size_t)m0 * D_DIM);
  const char* gB = (const char*)(Pf + (size_t)k0 * D_DIM);

  f32x4 acc[4][4] = {};

#define STAGE(buf, d0off)                                                         \
  do {                                                                            \
    _Pragma("unroll")                                                             \
    for (int is = 0; is < 4; is++) {                                              \
      const int chunk_ = wv * 4 + is;                                             \
      const size_t rb_ = (size_t)(chunk_ * 8 + srow) * (D_DIM * 2)                \
                       + (size_t)(d0off) * 2 + sswg;                              \
      gl16(gA + rb_, &Sh[buf][0][chunk_ * 512]);                                  \
      gl16(gB + rb_, &Sh[buf][1][chunk_ * 512]);                                  \
    }                                                                             \
  } while (0)

  STAGE(0, 0);
  __syncthreads();   // tile 0 resident

#pragma unroll
  for (int t = 0; t < 8; ++t) {
    const int cur = t & 1;
    if (t < 7) STAGE(cur ^ 1, (t + 1) * 64);   // prefetch next tile; latency hides under compute
    const unsigned short* Af = Sh[cur][0];
    const unsigned short* Bf = Sh[cur][1];

    // B fragments for both k-subtiles (slot j^(r&7) holds source granule j)
    f16x8 bv[2][4];
#pragma unroll
    for (int ks = 0; ks < 2; ks++)
#pragma unroll
      for (int ni = 0; ni < 4; ni++) {
        int rB = wn * 64 + ni * 16 + (lane & 15);
        int gBi = (ks * 4 + (lane >> 4)) ^ (rB & 7);
        bv[ks][ni] = *(const f16x8*)&Bf[rB * 64 + gBi * 8];
      }
#pragma unroll
    for (int mi = 0; mi < 4; mi++) {
      int rA = wm * 64 + mi * 16 + (lane & 15);
      int g0 = (0 + (lane >> 4)) ^ (rA & 7);
      int g1 = (4 + (lane >> 4)) ^ (rA & 7);
      f16x8 a0 = *(const f16x8*)&Af[rA * 64 + g0 * 8];
      f16x8 a1 = *(const f16x8*)&Af[rA * 64 + g1 * 8];
#pragma unroll
      for (int ni = 0; ni < 4; ni++) {
        acc[mi][ni] = __builtin_amdgcn_mfma_f32_16x16x32_f16(a0, bv[0][ni], acc[mi][ni], 0, 0, 0);
        acc[mi][ni] = __builtin_amdgcn_mfma_f32_16x16x32_f16(a1, bv[1][ni], acc[mi][ni], 0, 0, 0);
      }
    }
    __syncthreads();   // drains prefetch (vmcnt) + this tile's ds_reads before buffer reuse
  }
#undef STAGE

  // ---- epilogue: pack fp16 C-tile into LDS (stride 272B), then coalesced dwordx4 stores.
  unsigned short* Ct = &Sh[0][0][0];   // 128 * 136 halfs = 34,816 B, aliases staging (drained)
  float lmax = -3.4e38f;
#pragma unroll
  for (int mi = 0; mi < 4; mi++) {
    int rloc = wm * 64 + mi * 16 + (lane >> 4) * 4;
    float dxv[4];
#pragma unroll
    for (int r = 0; r < 4; r++) dxv[r] = xn[m0 + rloc + r];
#pragma unroll
    for (int ni = 0; ni < 4; ni++) {
      int cloc = wn * 64 + ni * 16 + (lane & 15);
      float pnc = pn[k0 + cloc];
#pragma unroll
      for (int r = 0; r < 4; r++) {
        float val = dxv[r] + pnc - 2.0f * acc[mi][ni][r];
        Ct[(rloc + r) * CT_STRIDE + cloc] = __half_as_ushort(__float2half(val));
        lmax = fmaxf(lmax, val);
      }
    }
  }
  __syncthreads();
  // 2048 16B-chunks (128 rows x 16); thread handles 8; 16 lanes cover one 256B row segment.
#pragma unroll
  for (int j = 0; j < 8; j++) {
    int idx = j * 256 + tid;
    int row = idx >> 4, cq = idx & 15;
    uint4 v = *(const uint4*)&Ct[row * CT_STRIDE + cq * 8];
    *(uint4*)&Ch[(size_t)(m0 + row) * K_PTS + k0 + cq * 8] = v;
  }

  lmax = wave_reduce_max(lmax);
  if (lane == 0) wmax[wv] = lmax;
  __syncthreads();
  if (tid == 0) {
    float m = fmaxf(fmaxf(wmax[0], wmax[1]), fmaxf(wmax[2], wmax[3]));
    atomicMax((int*)maxbits, __float_as_int(m));  // global max is positive
  }
}

// ---------------------------------------------------------------- persistent Sinkhorn, fully fused
// (unchanged from verified version)
__global__ __launch_bounds__(512, 2) void sinkhorn_kernel(
    const __half* __restrict__ Ch,
    const unsigned int* __restrict__ maxbits,
    float* __restrict__ accum,          // (ITERS+1) x NCOPY x K_PTS
    unsigned int* __restrict__ flags,   // SINK_BLOCKS x FLAG_STRIDE
    float* __restrict__ T,
    float* __restrict__ loss) {
  __shared__ float v_lds[K_PTS];
  __shared__ float red[8][K_PTS];
  const int tid = threadIdx.x;
  const int lane = tid & 63, wv = tid >> 6;
  const int b = blockIdx.x;
  const int r0 = b * 64 + wv * 8;

  float factor;
  {
    float cmax = __int_as_float((int)*maxbits);
    factor = -1.0f / ((cmax + 1e-8f) * EPS_F);
  }
  f32x4 k4[32];
#pragma unroll
  for (int i = 0; i < 8; i++) {
    const __half* rp = Ch + (size_t)(r0 + i) * K_PTS + lane;
#pragma unroll
    for (int q = 0; q < 4; q++) {
      f32x4 kk;
#pragma unroll
      for (int e = 0; e < 4; e++)
        kk[e] = __expf(__half2float(rp[(4 * q + e) * 64]) * factor);
      k4[i * 4 + q] = kk;
    }
  }
  v_lds[tid * 2 + 0] = 1.0f;
  v_lds[tid * 2 + 1] = 1.0f;
  __syncthreads();

  float su[8];
  for (int t = 0; t < ITERS; t++) {
    f32x4 vr4[4];
#pragma unroll
    for (int q = 0; q < 4; q++)
#pragma unroll
      for (int e = 0; e < 4; e++)
        vr4[q][e] = v_lds[(4 * q + e) * 64 + lane];

    float s[8];
#pragma unroll
    for (int i = 0; i < 8; i++) {
      f32x4 d = k4[i * 4 + 0] * vr4[0] + k4[i * 4 + 1] * vr4[1]
              + k4[i * 4 + 2] * vr4[2] + k4[i * 4 + 3] * vr4[3];
      s[i] = d[0] + d[1] + d[2] + d[3];
    }
    {
      const bool h32 = (lane & 32) != 0;
      float a[4];
#pragma unroll
      for (int i = 0; i < 4; i++) {
        float x = h32 ? s[i] : s[i + 4];
        float y = h32 ? s[i + 4] : s[i];
        a[i] = y + __shfl_xor(x, 32, 64);
      }
      const bool h16 = (lane & 16) != 0;
      float c[2];
#pragma unroll
      for (int i = 0; i < 2; i++) {
        float x = h16 ? a[i] : a[i + 2];
        float y = h16 ? a[i + 2] : a[i];
        c[i] = y + __shfl_xor(x, 16, 64);
      }
      const bool h8 = (lane & 8) != 0;
      float x = h8 ? c[0] : c[1];
      float y = h8 ? c[1] : c[0];
      float w = y + __shfl_xor(x, 8, 64);
      w += __shfl_xor(w, 4, 64);
      w += __shfl_xor(w, 2, 64);
      w += __shfl_xor(w, 1, 64);
      float ui_local = MU_F / (w + 1e-8f);
#pragma unroll
      for (int i = 0; i < 8; i++)
        su[i] = __uint_as_float(__builtin_amdgcn_readlane(__float_as_uint(ui_local), i * 8));
    }
    f32x4 ca4[4] = {};
#pragma unroll
    for (int i = 0; i < 8; i++)
#pragma unroll
      for (int q = 0; q < 4; q++)
        ca4[q] += su[i] * k4[i * 4 + q];

    __syncthreads();
#pragma unroll
    for (int q = 0; q < 4; q++)
#pragma unroll
      for (int e = 0; e < 4; e++)
        red[wv][(4 * q + e) * 64 + lane] = ca4[q][e];
    __syncthreads();
    {
      float s0 = 0.f, s1 = 0.f;
#pragma unroll
      for (int w8 = 0; w8 < 8; w8++) {
        float2 v2 = *(const float2*)&red[w8][tid * 2];
        s0 += v2.x; s1 += v2.y;
      }
      float* dst = accum + (size_t)(t + 1) * (NCOPY * K_PTS)
                 + (size_t)(b & (NCOPY - 1)) * K_PTS + tid * 2;
      atomicAdd(dst + 0, s0);
      atomicAdd(dst + 1, s1);
    }
    __syncthreads();
    if (tid == 0)
      __hip_atomic_store(&flags[(size_t)b * FLAG_STRIDE], (unsigned)(t + 1),
                         __ATOMIC_RELEASE, __HIP_MEMORY_SCOPE_AGENT);
    if (tid < SINK_BLOCKS) {
      while (__hip_atomic_load(&flags[(size_t)tid * FLAG_STRIDE],
                               __ATOMIC_RELAXED, __HIP_MEMORY_SCOPE_AGENT) < (unsigned)(t + 1))
        __builtin_amdgcn_s_sleep(4);
    }
    __syncthreads();
    {
      float* st = accum + (size_t)(t + 1) * (NCOPY * K_PTS);
      float s0 = 0.f, s1 = 0.f;
#pragma unroll
      for (int c = 0; c < NCOPY; c++) {  // agent-scope loads bypass stale caches (G16)
        s0 += __hip_atomic_load(st + (size_t)c * K_PTS + tid * 2 + 0,
                                __ATOMIC_RELAXED, __HIP_MEMORY_SCOPE_AGENT);
        s1 += __hip_atomic_load(st + (size_t)c * K_PTS + tid * 2 + 1,
                                __ATOMIC_RELAXED, __HIP_MEMORY_SCOPE_AGENT);
      }
      v_lds[tid * 2 + 0] = NU_F / (s0 + 1e-8f);
      v_lds[tid * 2 + 1] = NU_F / (s1 + 1e-8f);
    }
    __syncthreads();
  }

  float lsum = 0.f;
#pragma unroll
  for (int i = 0; i < 8; i++) {
    float* Trow = T + (size_t)(r0 + i) * K_PTS + lane;
#pragma unroll
    for (int q = 0; q < 4; q++) {
#pragma unroll
      for (int e = 0; e < 4; e++) {
        int c = (4 * q + e) * 64;
        float kk = k4[i * 4 + q][e];
        float tv = su[i] * kk * v_lds[c + lane];
        Trow[c] = tv;
        lsum += tv * (-EPS_F * __logf(kk));
      }
    }
  }
  lsum = wave_reduce_sum(lsum);
  __shared__ float wsum[8];
  if (lane == 0) wsum[wv] = lsum;
  __syncthreads();
  if (tid == 0) {
    float m = 0.f;
#pragma unroll
    for (int i = 0; i < 8; i++) m += wsum[i];
    atomicAdd(loss, m);
  }
}

// ---------------------------------------------------------------- launcher
extern "C" void kernel_launch(void* const* d_in, const int* in_sizes, int n_in,
                              void* d_out, int out_size, void* d_ws, size_t ws_size,
                              hipStream_t stream) {
  const float* x = (const float*)d_in[0];
  const float* p = (const float*)d_in[1];
  float* T = (float*)d_out;
  float* loss = (float*)d_out + (size_t)N_PTS * K_PTS;
  __half* Ch = (__half*)d_out;  // fp16 C staged in d_out[0, 32MiB)

  // f16 operands + norms live in d_out's upper half (dead until sinkhorn's final T write)
  unsigned short* Xf = (unsigned short*)((char*)d_out + ((size_t)32 << 20));
  unsigned short* Pf = (unsigned short*)((char*)d_out + ((size_t)48 << 20));
  float* xn = (float*)((char*)d_out + ((size_t)49 << 20));
  float* pn = xn + N_PTS;

  char* wsb = (char*)d_ws;
  float* accum = (float*)wsb;
  unsigned int* flags = (unsigned int*)(wsb + WS_ACCUM_BYTES);
  unsigned int* maxbits = (unsigned int*)(wsb + WS_ACCUM_BYTES + WS_FLAGS_BYTES);

  init_kernel<<<(ACC_TOTAL + 255) / 256, 256, 0, stream>>>(accum, flags, maxbits, loss);
  convert_kernel<<<(N_PTS + K_PTS) / 4, 256, 0, stream>>>(x, p, Xf, Pf, xn, pn);
  gemm4_kernel<<<dim3(K_PTS / 128, N_PTS / 128), 256, 0, stream>>>(Xf, Pf, xn, pn, Ch, maxbits);
  sinkhorn_kernel<<<SINK_BLOCKS, 512, 0, stream>>>(Ch, maxbits, accum, flags, T, loss);
}